// Round 11
// baseline (77.753 us; speedup 1.0000x reference)
//
#include <hip/hip_runtime.h>
#include <hip/hip_bf16.h>

// out = x @ bmat + h*a + (h@q) @ p^T ; M=64, N=K=8192, bmat f32 streamed once.
// Barrier-free streaming GEMM, 4KB block strips:
//  - wave = 64 rows x 128 cols; dwordx2 at j0+2*lane -> one 512B contiguous
//    row segment per instruction; 8 waves side-by-side -> 1024-col strip.
//  - B-fragments via v_permlane32_swap_b32 (pair rows i and i+8), 4 col-frags
//    per wave; depth-2 register pipeline; no barriers in the main loop.
//  - x f32->bf16 conversion fused into the block's LDS staging (x L3-resident).
// Partials bf16 [ks][64][8192], KSPLIT=32 (L3-resident) -> combine kernel.

#define HDIM 8192
#define BDIM 64
#define RDIM 4
#define KSPLIT 32
#define KSLAB 256            // HDIM / KSPLIT
#define NSTEP (KSLAB / 16)   // 16 k-steps of 16 rows

typedef short short8 __attribute__((ext_vector_type(8)));
typedef float f32x2 __attribute__((ext_vector_type(2)));
typedef float f32x4 __attribute__((ext_vector_type(4)));
typedef float f32x16 __attribute__((ext_vector_type(16)));

__device__ __forceinline__ unsigned f2bf(float f) {
  // round-to-nearest-even f32 -> bf16 (finite inputs); low 16 bits valid
  unsigned u = __float_as_uint(f);
  unsigned r = u + 0x7fffu + ((u >> 16) & 1u);
  return r >> 16;
}

__device__ __forceinline__ float bf2f(unsigned short u) {
  return __uint_as_float(((unsigned)u) << 16);
}

// ---- hq[b][r] = sum_k h[b][k] * q[k][r] ; one block per batch row ----
__global__ __launch_bounds__(256)
void hq_kernel(const float* __restrict__ h,
               const float* __restrict__ q,
               float* __restrict__ hq) {
  const int b = blockIdx.x, t = threadIdx.x;
  const float* hrow = h + (size_t)b * HDIM;
  f32x4 s = {0.f, 0.f, 0.f, 0.f};
  for (int k = t; k < HDIM; k += 256) {
    float hv = hrow[k];
    f32x4 qv = *(const f32x4*)(q + (size_t)k * RDIM);
    s += hv * qv;
  }
  __shared__ f32x4 red[256];
  red[t] = s;
  __syncthreads();
  for (int off = 128; off > 0; off >>= 1) {
    if (t < off) red[t] += red[t + off];
    __syncthreads();
  }
  if (t == 0) *(f32x4*)(hq + (size_t)b * RDIM) = red[0];
}

// ---- main: partial C for one (jg, ks): 64 rows x 1024 cols over K=256 ----
// x-LDS: 64 rows x 256 k bf16, 16B granules; phys granule g' = g ^ (row&7).
__global__ __launch_bounds__(512, 2)
void dplr_main(const float* __restrict__ bmat,
               const float* __restrict__ x,
               unsigned short* __restrict__ part) {
  __shared__ __align__(16) unsigned short xs[BDIM * KSLAB];  // 32 KiB

  const int t    = threadIdx.x;
  const int lane = t & 63;
  const int w    = t >> 6;        // 8 waves, wave w owns cols j0..j0+127
  const int c32  = lane & 31;
  const int kh   = lane >> 5;

  const int jg = blockIdx.x & 7;
  const int ks = blockIdx.x >> 3;
  const int k0 = ks * KSLAB;

  // ---- stage x slab (f32 -> bf16), rows 0..63, k in [k0, k0+256) ----
  {
    const int row  = t >> 3;
    const int koff = (t & 7) * 32;       // 32 f32 per thread
    const float* src = x + (size_t)row * HDIM + k0 + koff;
#pragma unroll
    for (int i = 0; i < 4; ++i) {
      f32x4 va = *(const f32x4*)(src + i * 8);
      f32x4 vb = *(const f32x4*)(src + i * 8 + 4);
      union { unsigned short u[8]; short8 s; } o;
#pragma unroll
      for (int e = 0; e < 4; ++e) {
        o.u[e]     = (unsigned short)f2bf(va[e]);
        o.u[4 + e] = (unsigned short)f2bf(vb[e]);
      }
      const int g  = row * (KSLAB / 8) + (t & 7) * 4 + i;
      const int gs = g ^ (row & 7);
      *(short8*)&xs[gs * 8] = o.s;
    }
  }
  __syncthreads();   // the only barrier in this kernel

  const int j0 = jg * 1024 + w * 128;
  const float* b0 = bmat + (size_t)k0 * HDIM + j0 + 2 * lane;

  f32x16 acc[2][4];   // [mt][n-frag], compile-time indexed after unroll
#pragma unroll
  for (int mt = 0; mt < 2; ++mt)
#pragma unroll
    for (int n = 0; n < 4; ++n)
#pragma unroll
      for (int r = 0; r < 16; ++r) acc[mt][n][r] = 0.f;

  f32x2 LA[16], LB[16];   // depth-2, 16 dwordx2 per 16-k step

  auto issue = [&](int kt, f32x2* L) {
#pragma unroll
    for (int i = 0; i < 16; ++i)
      L[i] = *(const f32x2*)(b0 + (size_t)(kt * 16 + i) * HDIM);
  };

  auto consume = [&](int kt, f32x2* L) {
    // pair rows i and i+8 across lane halves: after swap,
    //  L[i].c   lanes0-31 = row i   cols 2c32+c (group X)
    //  L[i].c   lanes32-63= row i+8 cols 2c32+c (group X)   -> frags 0,1
    //  L[i+8].c lanes0-31 = row i   cols 64+2c32+c (group Y)
    //  L[i+8].c lanes32-63= row i+8 cols 64+2c32+c          -> frags 2,3
#pragma unroll
    for (int i = 0; i < 8; ++i) {
      asm volatile("v_permlane32_swap_b32 %0, %1"
                   : "+v"(L[i].x), "+v"(L[i + 8].x));
      asm volatile("v_permlane32_swap_b32 %0, %1"
                   : "+v"(L[i].y), "+v"(L[i + 8].y));
    }
    union { unsigned u[4]; short8 v; } bf[4];
#pragma unroll
    for (int j = 0; j < 4; ++j) {
      bf[0].u[j] = f2bf(L[2 * j].x)     | (f2bf(L[2 * j + 1].x) << 16);
      bf[1].u[j] = f2bf(L[2 * j].y)     | (f2bf(L[2 * j + 1].y) << 16);
      bf[2].u[j] = f2bf(L[8 + 2 * j].x) | (f2bf(L[8 + 2 * j + 1].x) << 16);
      bf[3].u[j] = f2bf(L[8 + 2 * j].y) | (f2bf(L[8 + 2 * j + 1].y) << 16);
    }
#pragma unroll
    for (int mt = 0; mt < 2; ++mt) {
      const int row = mt * 32 + c32;
      const int g   = row * (KSLAB / 8) + kt * 2 + kh;
      const int gs  = g ^ (row & 7);
      short8 af = *(const short8*)&xs[gs * 8];
#pragma unroll
      for (int n = 0; n < 4; ++n)
        acc[mt][n] =
            __builtin_amdgcn_mfma_f32_32x32x16_bf16(af, bf[n].v, acc[mt][n], 0, 0, 0);
    }
  };

  issue(0, LA);
  issue(1, LB);
  for (int kt = 0; kt < NSTEP; kt += 2) {
    consume(kt, LA);
    if (kt + 2 < NSTEP) issue(kt + 2, LA);
    consume(kt + 1, LB);
    if (kt + 3 < NSTEP) issue(kt + 3, LB);
  }

  // partial write (bf16): part[ks][row][j]
  // C/D 32x32: col slot = lane&31, row = (reg&3) + 8*(reg>>2) + 4*kh
  // frag n real col: j0 + (n>=2)*64 + 2*c32 + (n&1)
  unsigned short* pb = part + (size_t)ks * BDIM * HDIM;
#pragma unroll
  for (int mt = 0; mt < 2; ++mt)
#pragma unroll
    for (int n = 0; n < 4; ++n) {
      const int col = j0 + ((n >> 1) * 64) + 2 * c32 + (n & 1);
#pragma unroll
      for (int reg = 0; reg < 16; ++reg) {
        const int row = mt * 32 + (reg & 3) + 8 * (reg >> 2) + 4 * kh;
        pb[(size_t)row * HDIM + col] = (unsigned short)f2bf(acc[mt][n][reg]);
      }
    }
}

// ---- combine: out = sum_ks part + h*a + hq @ p^T ----
__global__ __launch_bounds__(256)
void combine_kernel(const unsigned short* __restrict__ part,
                    const float* __restrict__ h,
                    const float* __restrict__ adiag,
                    const float* __restrict__ pvec,
                    const float* __restrict__ hq,
                    float* __restrict__ out) {
  const int tid  = blockIdx.x * 256 + threadIdx.x;
  const int base = tid * 8;            // flat into [64][8192]
  const int row  = base >> 13;
  const int j    = base & 8191;

  float s[8];
#pragma unroll
  for (int e = 0; e < 8; ++e) s[e] = 0.f;
  const unsigned short* pp = part + (size_t)row * HDIM + j;
#pragma unroll
  for (int ks = 0; ks < KSPLIT; ++ks) {
    union { unsigned short u[8]; short8 v; } pv;
    pv.v = *(const short8*)(pp + (size_t)ks * BDIM * HDIM);
#pragma unroll
    for (int e = 0; e < 8; ++e) s[e] += bf2f(pv.u[e]);
  }
  const f32x4 hv0 = *(const f32x4*)(h + (size_t)row * HDIM + j);
  const f32x4 hv1 = *(const f32x4*)(h + (size_t)row * HDIM + j + 4);
  const f32x4 a0  = *(const f32x4*)(adiag + j);
  const f32x4 a1  = *(const f32x4*)(adiag + j + 4);
  const f32x4 hqv = *(const f32x4*)(hq + (size_t)row * RDIM);

  float res[8];
#pragma unroll
  for (int e = 0; e < 4; ++e) {
    const f32x4 pv = *(const f32x4*)(pvec + (size_t)(j + e) * RDIM);
    res[e] = s[e] + hv0[e] * a0[e] +
             hqv[0] * pv[0] + hqv[1] * pv[1] + hqv[2] * pv[2] + hqv[3] * pv[3];
  }
#pragma unroll
  for (int e = 0; e < 4; ++e) {
    const f32x4 pv = *(const f32x4*)(pvec + (size_t)(j + 4 + e) * RDIM);
    res[4 + e] = s[4 + e] + hv1[e] * a1[e] +
                 hqv[0] * pv[0] + hqv[1] * pv[1] + hqv[2] * pv[2] + hqv[3] * pv[3];
  }
  f32x4 o0 = {res[0], res[1], res[2], res[3]};
  f32x4 o1 = {res[4], res[5], res[6], res[7]};
  *(f32x4*)(out + (size_t)row * HDIM + j) = o0;
  *(f32x4*)(out + (size_t)row * HDIM + j + 4) = o1;
}

extern "C" void kernel_launch(void* const* d_in, const int* in_sizes, int n_in,
                              void* d_out, int out_size, void* d_ws, size_t ws_size,
                              hipStream_t stream) {
  const float* h     = (const float*)d_in[0];
  const float* x     = (const float*)d_in[1];
  const float* adiag = (const float*)d_in[2];
  const float* pvec  = (const float*)d_in[3];
  const float* qvec  = (const float*)d_in[4];
  const float* bmat  = (const float*)d_in[5];
  float* out = (float*)d_out;

  float* hqbuf = (float*)d_ws;                                          // 1 KiB
  unsigned short* part = (unsigned short*)((char*)d_ws + ((size_t)1 << 20));  // 32 MiB

  hq_kernel<<<BDIM, 256, 0, stream>>>(h, qvec, hqbuf);
  dplr_main<<<KSPLIT * 8, 512, 0, stream>>>(bmat, x, part);
  combine_kernel<<<(BDIM * HDIM / 8) / 256, 256, 0, stream>>>(part, h, adiag, pvec, hqbuf, out);
}